// Round 18
// baseline (443.482 us; speedup 1.0000x reference)
//
#include <hip/hip_runtime.h>
#include <hip/hip_bf16.h>
#include <cstdint>
#include <cstddef>

#define FIN      128
#define HGAT_H   4
#define HGAT_C   64
#define HGAT_HC  256
#define NGRAPHS  64
#define NACT     32
#define LOG2E    1.4426950408889634f
#define CNT_BLOCKS 128

typedef unsigned int   uint32;
typedef unsigned short ushort_t;

using short8 = __attribute__((ext_vector_type(8))) short;
using u16x8  = __attribute__((ext_vector_type(8))) ushort_t;
using f32x4  = __attribute__((ext_vector_type(4))) float;
using f32x2  = __attribute__((ext_vector_type(2))) float;

__device__ __forceinline__ float bf2f(ushort_t u) {
    return __uint_as_float(((uint32)u) << 16);
}
__device__ __forceinline__ float bflo(uint32 q) {
    return __uint_as_float(q << 16);
}
__device__ __forceinline__ float bfhi(uint32 q) {
    return __uint_as_float(q & 0xFFFF0000u);
}
__device__ __forceinline__ ushort_t f2bf(float f) {
    __hip_bfloat16 h = __float2bfloat16(f);   // RNE
    return *reinterpret_cast<ushort_t*>(&h);
}

// ---------------------------------------------------------------------------
// attB fold helper (hi/lo bf16 split, stored transposed [16][K]).
// ---------------------------------------------------------------------------
__device__ __forceinline__ void att_fold_one(
    const float* __restrict__ W, const float* __restrict__ as,
    const float* __restrict__ ad, ushort_t* __restrict__ attBt,
    int K, int idx)
{
    const int k = idx >> 3, j = idx & 7;
    const int h = j >> 1;
    const float* av = (j & 1) ? ad : as;
    float s = 0.f;
#pragma unroll 8
    for (int c = 0; c < HGAT_C; ++c)
        s += W[(size_t)k * HGAT_HC + h * 64 + c] * av[h * 64 + c];
    const ushort_t hi = f2bf(s);
    const float    lo = s - bf2f(hi);
    attBt[(size_t)j * K + k]       = hi;
    attBt[(size_t)(j + 8) * K + k] = f2bf(lo);
}

// ---------------------------------------------------------------------------
// Merged: per-bucket edge histogram + weight/att prep (unchanged from r17).
// ---------------------------------------------------------------------------
__global__ __launch_bounds__(256) void bucket_count_prep_kernel(
    const int* __restrict__ ei, int* __restrict__ bhist,
    const float* __restrict__ W1, const float* __restrict__ W2,
    const float* __restrict__ as1, const float* __restrict__ ad1,
    const float* __restrict__ as2, const float* __restrict__ ad2,
    ushort_t* __restrict__ Wt1, ushort_t* __restrict__ Wt2,
    ushort_t* __restrict__ attBt1, ushort_t* __restrict__ attBt2, int E)
{
    const int t = threadIdx.x;
    if (blockIdx.x < CNT_BLOCKS) {
        __shared__ int hist[256];
        hist[t] = 0;
        __syncthreads();
        const int chunk = (E + CNT_BLOCKS - 1) / CNT_BLOCKS;
        const int lo = blockIdx.x * chunk;
        const int hi = min(lo + chunk, E);
        for (int e = lo + t; e < hi; e += 256)
            atomicAdd(&hist[ei[E + e] >> 8], 1);
        __syncthreads();
        bhist[blockIdx.x * 256 + t] = hist[t];
        return;
    }
    const int idx = (blockIdx.x - CNT_BLOCKS) * 256 + t;
    const int n1 = FIN * HGAT_HC;
    const int n2 = HGAT_HC * HGAT_HC;
    if (idx < n1) {
        const int k = idx >> 8, c = idx & 255;
        Wt1[(size_t)c * FIN + k] = f2bf(W1[idx]);
    } else if (idx < n1 + n2) {
        const int j = idx - n1;
        const int k = j >> 8, c = j & 255;
        Wt2[(size_t)c * HGAT_HC + k] = f2bf(W2[j]);
    } else if (idx < n1 + n2 + FIN * 8) {
        att_fold_one(W1, as1, ad1, attBt1, FIN, idx - n1 - n2);
    } else if (idx < n1 + n2 + (FIN + HGAT_HC) * 8) {
        att_fold_one(W2, as2, ad2, attBt2, HGAT_HC, idx - n1 - n2 - FIN * 8);
    }
}

__global__ __launch_bounds__(256) void bucket_scan_kernel(
    const int* __restrict__ bhist, int* __restrict__ boff,
    int* __restrict__ bcur)
{
    __shared__ int sm[256];
    const int t = threadIdx.x;
    int v = 0;
    for (int j = 0; j < CNT_BLOCKS; ++j) v += bhist[j * 256 + t];
    sm[t] = v;
    __syncthreads();
#pragma unroll
    for (int off = 1; off < 256; off <<= 1) {
        const int u = (t >= off) ? sm[t - off] : 0;
        __syncthreads();
        sm[t] += u;
        __syncthreads();
    }
    const int ex = sm[t] - v;
    boff[t] = ex;
    bcur[t] = ex;
    if (t == 255) boff[256] = sm[255];
}

__device__ __forceinline__ void scatter_body(
    const int* __restrict__ ei, int* __restrict__ bcur,
    int2* __restrict__ staging, int E, int blk)
{
    __shared__ int hist[256];
    __shared__ int base[256];
    __shared__ int cur[256];
    const int t = threadIdx.x;
    hist[t] = 0;
    __syncthreads();

    const int chunk = 4096;
    const int lo = blk * chunk;
    const int hi = min(lo + chunk, E);

    for (int e = lo + t; e < hi; e += 256)
        atomicAdd(&hist[ei[E + e] >> 8], 1);
    __syncthreads();
    if (hist[t] > 0) base[t] = atomicAdd(&bcur[t], hist[t]);
    cur[t] = 0;
    __syncthreads();

    for (int e = lo + t; e < hi; e += 256) {
        const int s = ei[e];
        const int d = ei[E + e];
        const int b = d >> 8;
        const int r = atomicAdd(&cur[b], 1);
        staging[base[b] + r] = make_int2(s, d);
    }
}

__global__ __launch_bounds__(256) void bucket_fill_kernel(
    const int2* __restrict__ staging, const int* __restrict__ boff,
    int* __restrict__ rowptr, int* __restrict__ colsrc, int N, int E)
{
    __shared__ int deg[256];
    __shared__ int ssc[256];
    __shared__ int cur[256];
    const int t  = threadIdx.x;
    const int b  = blockIdx.x;
    const int lo = boff[b];
    const int hi = boff[b + 1];

    deg[t] = 0;
    __syncthreads();
    for (int e = lo + t; e < hi; e += 256)
        atomicAdd(&deg[staging[e].y & 255], 1);
    __syncthreads();

    const int v = deg[t];
    ssc[t] = v;
    __syncthreads();
#pragma unroll
    for (int off = 1; off < 256; off <<= 1) {
        const int u = (t >= off) ? ssc[t - off] : 0;
        __syncthreads();
        ssc[t] += u;
        __syncthreads();
    }
    const int pre  = ssc[t] - v;
    const int node = b * 256 + t;
    if (node < N) rowptr[node] = lo + pre;
    cur[t] = lo + pre;
    if (b == 0 && t == 0) rowptr[N] = E;
    __syncthreads();

    for (int e = lo + t; e < hi; e += 256) {
        const int2 sd = staging[e];
        const int pos = atomicAdd(&cur[sd.y & 255], 1);
        colsrc[pos] = sd.x;
    }
}

// ---------------------------------------------------------------------------
// GEMM body.  C written TRANSPOSED: hbT[slice][node][32], slice = ch>>5
// (3.2MB per slice -> one XCD's L2 can hold it for the sliced aggregate).
// Everything else unchanged from r17.
// ---------------------------------------------------------------------------
template <int K, bool AF32>
__device__ __forceinline__ void gemm_body(
    const void* __restrict__ Av, const ushort_t* __restrict__ Bt,
    const ushort_t* __restrict__ attBt, ushort_t* __restrict__ CbT,
    float* __restrict__ a_src, float* __restrict__ a_dst, int M, int blk)
{
    constexpr int KK   = K / 32;
    constexpr int NPF  = K / 32;
    constexpr int BSTR = K + 8;
    constexpr int CSTR = 72;
    __shared__ ushort_t Bs[64 * BSTR];
    __shared__ ushort_t AttS[16 * BSTR];
    __shared__ ushort_t Cs[64 * CSTR];

    const int t  = threadIdx.x;
    const int w  = t >> 6;
    const int l  = t & 63;
    const int lg = l >> 4;
    const int lr = l & 15;
    const int rowbase = blk * 64 + w * 16;

    const int srow  = t & 63;
    const int cbase = (t >> 6) * (K / 4);

    short8 af[KK];
    {
        const int arow = rowbase + lr;
        const int gr   = arow < M ? arow : M - 1;
        if (AF32) {
            const float* Ap = (const float*)Av + (size_t)gr * K;
#pragma unroll
            for (int kk = 0; kk < KK; ++kk) {
                const float4 v0 = *reinterpret_cast<const float4*>(Ap + kk * 32 + lg * 8);
                const float4 v1 = *reinterpret_cast<const float4*>(Ap + kk * 32 + lg * 8 + 4);
                short8 s;
                s[0] = (short)f2bf(v0.x); s[1] = (short)f2bf(v0.y);
                s[2] = (short)f2bf(v0.z); s[3] = (short)f2bf(v0.w);
                s[4] = (short)f2bf(v1.x); s[5] = (short)f2bf(v1.y);
                s[6] = (short)f2bf(v1.z); s[7] = (short)f2bf(v1.w);
                af[kk] = s;
            }
        } else {
            const ushort_t* Ap = (const ushort_t*)Av + (size_t)gr * K;
#pragma unroll
            for (int kk = 0; kk < KK; ++kk)
                af[kk] = *reinterpret_cast<const short8*>(Ap + kk * 32 + lg * 8);
        }
    }

    {
        const int r  = t & 15;
        const int cb = (t >> 4) * (K / 16);
        const ushort_t* src = attBt + (size_t)r * K + cb;
        ushort_t*       dst = &AttS[r * BSTR + cb];
#pragma unroll
        for (int j = 0; j < K / 128; ++j)
            *reinterpret_cast<u16x8*>(dst + j * 8) =
                *reinterpret_cast<const u16x8*>(src + j * 8);
    }
    {
        const ushort_t* src = Bt + (size_t)srow * K + cbase;
        ushort_t*       dst = &Bs[srow * BSTR + cbase];
#pragma unroll
        for (int j = 0; j < NPF; ++j)
            *reinterpret_cast<u16x8*>(dst + j * 8) =
                *reinterpret_cast<const u16x8*>(src + j * 8);
    }
    __syncthreads();

    {
        f32x4 aacc = {0.f, 0.f, 0.f, 0.f};
#pragma unroll
        for (int kk = 0; kk < KK; ++kk) {
            const short8 bfr = *reinterpret_cast<const short8*>(
                &AttS[lr * BSTR + kk * 32 + lg * 8]);
            aacc = __builtin_amdgcn_mfma_f32_16x16x32_bf16(af[kk], bfr, aacc, 0, 0, 0);
        }
#pragma unroll
        for (int reg = 0; reg < 4; ++reg) {
            const int gm = rowbase + lg * 4 + reg;
            const float v = aacc[reg] + __shfl_xor(aacc[reg], 8);   // hi + lo
            if (lr < 8 && gm < M) {
                const int hh = lr >> 1;
                if (lr & 1) a_dst[gm * 4 + hh] = v * LOG2E;
                else        a_src[gm * 4 + hh] = v * LOG2E;
            }
        }
    }

    u16x8 pf[NPF];
#pragma unroll
    for (int head = 0; head < HGAT_H; ++head) {
        if (head < HGAT_H - 1) {
            const ushort_t* src =
                Bt + ((size_t)(head + 1) * 64 + srow) * K + cbase;
#pragma unroll
            for (int j = 0; j < NPF; ++j)
                pf[j] = *reinterpret_cast<const u16x8*>(src + j * 8);
        }

        f32x4 acc[4];
#pragma unroll
        for (int ct = 0; ct < 4; ++ct) acc[ct] = {0.f, 0.f, 0.f, 0.f};

#pragma unroll
        for (int kk = 0; kk < KK; ++kk) {
            short8 bfr[4];
#pragma unroll
            for (int ct = 0; ct < 4; ++ct)
                bfr[ct] = *reinterpret_cast<const short8*>(
                    &Bs[(ct * 16 + lr) * BSTR + kk * 32 + lg * 8]);
#pragma unroll
            for (int ct = 0; ct < 4; ++ct)
                acc[ct] = __builtin_amdgcn_mfma_f32_16x16x32_bf16(
                    af[kk], bfr[ct], acc[ct], 0, 0, 0);
        }

#pragma unroll
        for (int reg = 0; reg < 4; ++reg) {
            const int r = w * 16 + lg * 4 + reg;
#pragma unroll
            for (int ct = 0; ct < 4; ++ct)
                Cs[r * CSTR + ct * 16 + lr] = f2bf(acc[ct][reg]);
        }
        __syncthreads();

        // transposed copy-out: ch = head*64 + cc; slice = ch>>5
        {
            const int cc = (t & 7) * 8;
            const int ch = head * 64 + cc;
            const int slice  = ch >> 5;
            const int within = ch & 31;
#pragma unroll
            for (int it = 0; it < 2; ++it) {
                const int r  = (t >> 3) + it * 32;
                const int gm = blk * 64 + r;
                if (gm < M) {
                    const u16x8 val = *reinterpret_cast<const u16x8*>(&Cs[r * CSTR + cc]);
                    *reinterpret_cast<u16x8*>(
                        &CbT[((size_t)slice * M + gm) * 32 + within]) = val;
                }
            }
        }

        if (head < HGAT_H - 1) {
            ushort_t* dst = &Bs[srow * BSTR + cbase];
#pragma unroll
            for (int j = 0; j < NPF; ++j)
                *reinterpret_cast<u16x8*>(dst + j * 8) = pf[j];
        }
        __syncthreads();
    }
}

__global__ __launch_bounds__(256) void scatter_gemm1_kernel(
    const int* __restrict__ ei, int* __restrict__ bcur,
    int2* __restrict__ staging, int E, int SB,
    const float* __restrict__ x, const ushort_t* __restrict__ Wt1,
    const ushort_t* __restrict__ attBt1, ushort_t* __restrict__ hbT,
    float* __restrict__ a_src, float* __restrict__ a_dst, int M)
{
    if ((int)blockIdx.x < SB) {
        scatter_body(ei, bcur, staging, E, blockIdx.x);
        return;
    }
    gemm_body<FIN, true>(x, Wt1, attBt1, hbT, a_src, a_dst, M,
                         blockIdx.x - SB);
}

__global__ __launch_bounds__(256) void gemm2_kernel(
    const ushort_t* __restrict__ A, const ushort_t* __restrict__ Wt2,
    const ushort_t* __restrict__ attBt2, ushort_t* __restrict__ hbT,
    float* __restrict__ a_src, float* __restrict__ a_dst, int M)
{
    gemm_body<HGAT_HC, false>(A, Wt2, attBt2, hbT, a_src, a_dst, M, blockIdx.x);
}

// ---------------------------------------------------------------------------
// XCD-sliced aggregate: slice = blockIdx&7 (round-robin block->XCD pins each
// 3.2MB hbT slice to one XCD's L2). Wave = 1 node: 16 edge-slots x 4 ch-quads
// (uint4/lane). Slot-tree reduce via shfl_xor(4,8,16,32).
// MODE 0: + bias + ELU -> bf16 out[N,256] (standard layout, feeds gemm2).
// MODE 1: raw weighted means -> bf16 out[N,256]; head-mean+bias+ELU in pool.
// ---------------------------------------------------------------------------
template <int MODE>
__global__ __launch_bounds__(256) void aggregate_slice_kernel(
    const int* __restrict__ rowptr, const int* __restrict__ colsrc,
    const ushort_t* __restrict__ hbT, const float* __restrict__ a_src,
    const float* __restrict__ a_dst, const float* __restrict__ bias,
    ushort_t* __restrict__ out, int N)
{
    const int slice = blockIdx.x & 7;
    const int node  = (blockIdx.x >> 3) * 4 + (threadIdx.x >> 6);
    if (node >= N) return;
    const int lane = threadIdx.x & 63;
    const int slot = lane >> 2;     // 0..15 edge slot
    const int q    = lane & 3;      // channel quad (8 ch)
    const int head = slice >> 1;
    const ushort_t* hs = hbT + (size_t)slice * N * 32;
    const float ad = a_dst[node * 4 + head];

    float vv[9];   // 8 ch accum + den
#pragma unroll
    for (int j = 0; j < 9; ++j) vv[j] = 0.f;

    const int beg = rowptr[node], end = rowptr[node + 1];
    for (int base = beg; base < end; base += 16) {
        const int idx   = base + slot;
        const bool ok   = idx < end;
        const int s     = colsrc[ok ? idx : end - 1];
        const float a   = a_src[s * 4 + head];
        float ee = a + ad;
        ee = fmaxf(ee, 0.2f * ee);
        const float w = ok ? __builtin_amdgcn_exp2f(ee) : 0.f;
        const uint4 qv = *reinterpret_cast<const uint4*>(
            hs + (size_t)s * 32 + q * 8);
        vv[0] += w * bflo(qv.x); vv[1] += w * bfhi(qv.x);
        vv[2] += w * bflo(qv.y); vv[3] += w * bfhi(qv.y);
        vv[4] += w * bflo(qv.z); vv[5] += w * bfhi(qv.z);
        vv[6] += w * bflo(qv.w); vv[7] += w * bfhi(qv.w);
        vv[8] += w;
    }
    if (slot == 0) {   // self loop, once per quad-group
        const float a = a_src[node * 4 + head];
        float ee = a + ad;
        ee = fmaxf(ee, 0.2f * ee);
        const float w = __builtin_amdgcn_exp2f(ee);
        const uint4 qv = *reinterpret_cast<const uint4*>(
            hs + (size_t)node * 32 + q * 8);
        vv[0] += w * bflo(qv.x); vv[1] += w * bfhi(qv.x);
        vv[2] += w * bflo(qv.y); vv[3] += w * bfhi(qv.y);
        vv[4] += w * bflo(qv.z); vv[5] += w * bfhi(qv.z);
        vv[6] += w * bflo(qv.w); vv[7] += w * bfhi(qv.w);
        vv[8] += w;
    }

    // reduce across 16 slots (lanes with same q)
#pragma unroll
    for (int off = 4; off < 64; off <<= 1)
#pragma unroll
        for (int j = 0; j < 9; ++j) vv[j] += __shfl_xor(vv[j], off);

    if (slot == 0) {
        const float inv = 1.0f / vv[8];
        const int chb = slice * 32 + q * 8;
        u16x8 u;
        if (MODE == 0) {
            const float4 b0 = *reinterpret_cast<const float4*>(&bias[chb]);
            const float4 b1 = *reinterpret_cast<const float4*>(&bias[chb + 4]);
            const float bb[8] = {b0.x, b0.y, b0.z, b0.w, b1.x, b1.y, b1.z, b1.w};
#pragma unroll
            for (int j = 0; j < 8; ++j) {
                float r = vv[j] * inv + bb[j];
                r = r > 0.f ? r : expm1f(r);
                u[j] = f2bf(r);
            }
        } else {
#pragma unroll
            for (int j = 0; j < 8; ++j) u[j] = f2bf(vv[j] * inv);
        }
        *reinterpret_cast<u16x8*>(&out[(size_t)node * HGAT_HC + chb]) = u;
    }
}

// ---------------------------------------------------------------------------
// Pool stage A: fuses head-mean + bias + ELU (reads hmid[N][256] raw means).
// ---------------------------------------------------------------------------
__device__ __forceinline__ int lower_bound_batch(
    const int* __restrict__ batch, int N, int key)
{
    int lo = 0, hi = N;
    while (lo < hi) {
        const int mid = (lo + hi) >> 1;
        if (batch[mid] < key) lo = mid + 1; else hi = mid;
    }
    return lo;
}

__global__ __launch_bounds__(256) void pool_partial_kernel(
    const ushort_t* __restrict__ hmid, const int* __restrict__ batch,
    const float* __restrict__ b2, float* __restrict__ partial, int N)
{
    const int g   = blockIdx.x >> 3;
    const int s   = blockIdx.x & 7;
    const int t   = threadIdx.x;
    const int c   = t & 63;
    const int sub = t >> 6;

    const int beg = lower_bound_batch(batch, N, g);
    const int end = lower_bound_batch(batch, N, g + 1);
    const int len = end - beg;
    const int sl  = (len + 7) >> 3;
    const int sb  = beg + s * sl;
    const int se  = sb + sl < end ? sb + sl : end;

    const float bc = b2[c];
    float acc = 0.f;
    for (int n = sb + sub; n < se; n += 4) {
        const ushort_t* row = hmid + (size_t)n * HGAT_HC;
        float m = 0.25f * (bf2f(row[c]) + bf2f(row[64 + c]) +
                           bf2f(row[128 + c]) + bf2f(row[192 + c])) + bc;
        acc += m > 0.f ? m : expm1f(m);
    }

    __shared__ float sm[256];
    sm[t] = acc;
    __syncthreads();
    if (sub == 0)
        partial[(size_t)(g * 8 + s) * HGAT_C + c] =
            sm[c] + sm[64 + c] + sm[128 + c] + sm[192 + c];
}

__global__ __launch_bounds__(64) void pool_final_fused_kernel(
    const float* __restrict__ partial, const int* __restrict__ batch,
    const float* __restrict__ Wa, const float* __restrict__ ba,
    float* __restrict__ out, int N)
{
    const int g = blockIdx.x;
    const int c = threadIdx.x;
    const int beg = lower_bound_batch(batch, N, g);
    const int end = lower_bound_batch(batch, N, g + 1);
    float s = 0.f;
#pragma unroll
    for (int k = 0; k < 8; ++k)
        s += partial[(size_t)(g * 8 + k) * HGAT_C + c];
    s /= fmaxf((float)(end - beg), 1.0f);

    __shared__ float pr[HGAT_C];
    pr[c] = s;
    __syncthreads();
    if (c < NACT) {
        float o = ba[c];
#pragma unroll
        for (int cc = 0; cc < HGAT_C; ++cc)
            o += pr[cc] * Wa[cc * NACT + c];
        out[g * NACT + c] = o;
    }
}

// ---------------------------------------------------------------------------
extern "C" void kernel_launch(void* const* d_in, const int* in_sizes, int n_in,
                              void* d_out, int out_size, void* d_ws, size_t ws_size,
                              hipStream_t stream)
{
    const float* x     = (const float*)d_in[0];
    const int*   ei    = (const int*)d_in[1];
    const int*   batch = (const int*)d_in[2];
    const float* W1    = (const float*)d_in[5];
    const float* as1   = (const float*)d_in[6];
    const float* ad1   = (const float*)d_in[7];
    const float* b1    = (const float*)d_in[8];
    const float* W2    = (const float*)d_in[9];
    const float* as2   = (const float*)d_in[10];
    const float* ad2   = (const float*)d_in[11];
    const float* b2    = (const float*)d_in[12];
    const float* Wa    = (const float*)d_in[13];
    const float* ba    = (const float*)d_in[14];

    const int N = in_sizes[0] / FIN;
    const int E = in_sizes[1] / 2;

    char* ws = (char*)d_ws;
    size_t off = 0;
    auto alloc = [&](size_t bytes) -> void* {
        void* p = ws + off;
        off += (bytes + 255) & ~(size_t)255;
        return p;
    };
    ushort_t* hbT     = (ushort_t*)alloc((size_t)N * HGAT_HC * 2);  // [8][N][32]
    ushort_t* hpost   = (ushort_t*)alloc((size_t)N * HGAT_HC * 2);  // L1 out / hmid
    ushort_t* Wt1     = (ushort_t*)alloc((size_t)FIN * HGAT_HC * 2);
    ushort_t* Wt2     = (ushort_t*)alloc((size_t)HGAT_HC * HGAT_HC * 2);
    ushort_t* attBt1  = (ushort_t*)alloc((size_t)16 * FIN * 2);
    ushort_t* attBt2  = (ushort_t*)alloc((size_t)16 * HGAT_HC * 2);
    float*    a_src   = (float*)alloc((size_t)N * 4 * 4);
    float*    a_dst   = (float*)alloc((size_t)N * 4 * 4);
    int*      rowptr  = (int*)alloc((size_t)(N + 1) * 4);
    int*      colsrc  = (int*)alloc((size_t)E * 4);
    int2*     staging = (int2*)alloc((size_t)E * 8);
    int*      bhist   = (int*)alloc((size_t)CNT_BLOCKS * 256 * 4);
    int*      boff    = (int*)alloc(257 * 4);
    int*      bcur    = (int*)alloc(256 * 4);
    float*    partial = (float*)alloc((size_t)NGRAPHS * 8 * HGAT_C * 4);
    ushort_t* hmid    = hpost;   // reuse: hpost consumed by gemm2 before agg<1>
    (void)ws_size; (void)n_in; (void)out_size;

    const int gemmBlocks = (N + 63) / 64;
    const int aggBlocks  = ((N + 3) / 4) * 8;   // node-chunks x 8 slices
    const int NBKT       = (N + 255) >> 8;
    const int SB         = (E + 4095) / 4096;
    const int prepTot    = FIN * HGAT_HC + HGAT_HC * HGAT_HC + (FIN + HGAT_HC) * 8;
    const int prepBlocks = (prepTot + 255) / 256;

    // ---------------- dispatch 1: edge histograms + prep ----------------
    bucket_count_prep_kernel<<<CNT_BLOCKS + prepBlocks, 256, 0, stream>>>(
        ei, bhist, W1, W2, as1, ad1, as2, ad2, Wt1, Wt2, attBt1, attBt2, E);

    // ---------------- dispatch 2: hist-sum + bucket scan ----------------
    bucket_scan_kernel<<<1, 256, 0, stream>>>(bhist, boff, bcur);

    // ---------------- dispatch 3: scatter || GEMM1 ----------------
    scatter_gemm1_kernel<<<SB + gemmBlocks, 256, 0, stream>>>(
        ei, bcur, staging, E, SB, x, Wt1, attBt1, hbT, a_src, a_dst, N);

    // ---------------- dispatch 4: bucket fill ----------------
    bucket_fill_kernel<<<NBKT, 256, 0, stream>>>(
        staging, boff, rowptr, colsrc, N, E);

    // ---------------- layer 1 aggregate (XCD-sliced) ----------------
    aggregate_slice_kernel<0><<<aggBlocks, 256, 0, stream>>>(
        rowptr, colsrc, hbT, a_src, a_dst, b1, hpost, N);

    // ---------------- layer 2 ----------------
    gemm2_kernel<<<gemmBlocks, 256, 0, stream>>>(
        hpost, Wt2, attBt2, hbT, a_src, a_dst, N);
    aggregate_slice_kernel<1><<<aggBlocks, 256, 0, stream>>>(
        rowptr, colsrc, hbT, a_src, a_dst, b2, hmid, N);

    // ---------------- pool (head-mean fused) + final ----------------
    pool_partial_kernel<<<NGRAPHS * 8, 256, 0, stream>>>(
        hmid, batch, b2, partial, N);
    pool_final_fused_kernel<<<NGRAPHS, 64, 0, stream>>>(
        partial, batch, Wa, ba, (float*)d_out, N);
}

// Round 19
// 225.948 us; speedup vs baseline: 1.9628x; 1.9628x over previous
//
#include <hip/hip_runtime.h>
#include <hip/hip_bf16.h>
#include <cstdint>
#include <cstddef>

#define FIN      128
#define HGAT_H   4
#define HGAT_C   64
#define HGAT_HC  256
#define NGRAPHS  64
#define NACT     32
#define LOG2E    1.4426950408889634f
#define CNT_BLOCKS 128

typedef unsigned int   uint32;
typedef unsigned short ushort_t;

using short8 = __attribute__((ext_vector_type(8))) short;
using u16x8  = __attribute__((ext_vector_type(8))) ushort_t;
using f32x4  = __attribute__((ext_vector_type(4))) float;
using f32x2  = __attribute__((ext_vector_type(2))) float;

__device__ __forceinline__ float bf2f(ushort_t u) {
    return __uint_as_float(((uint32)u) << 16);
}
__device__ __forceinline__ float bflo(uint32 q) {
    return __uint_as_float(q << 16);
}
__device__ __forceinline__ float bfhi(uint32 q) {
    return __uint_as_float(q & 0xFFFF0000u);
}
__device__ __forceinline__ ushort_t f2bf(float f) {
    __hip_bfloat16 h = __float2bfloat16(f);   // RNE
    return *reinterpret_cast<ushort_t*>(&h);
}

// ---------------------------------------------------------------------------
// attB fold helper (hi/lo bf16 split, stored transposed [16][K]).
// ---------------------------------------------------------------------------
__device__ __forceinline__ void att_fold_one(
    const float* __restrict__ W, const float* __restrict__ as,
    const float* __restrict__ ad, ushort_t* __restrict__ attBt,
    int K, int idx)
{
    const int k = idx >> 3, j = idx & 7;
    const int h = j >> 1;
    const float* av = (j & 1) ? ad : as;
    float s = 0.f;
#pragma unroll 8
    for (int c = 0; c < HGAT_C; ++c)
        s += W[(size_t)k * HGAT_HC + h * 64 + c] * av[h * 64 + c];
    const ushort_t hi = f2bf(s);
    const float    lo = s - bf2f(hi);
    attBt[(size_t)j * K + k]       = hi;
    attBt[(size_t)(j + 8) * K + k] = f2bf(lo);
}

// ---------------------------------------------------------------------------
// Merged: per-bucket edge histogram (bucket = dst>>8, per-block hist rows,
// no global atomics, no memset) + weight/att prep.
// ---------------------------------------------------------------------------
__global__ __launch_bounds__(256) void bucket_count_prep_kernel(
    const int* __restrict__ ei, int* __restrict__ bhist,
    const float* __restrict__ W1, const float* __restrict__ W2,
    const float* __restrict__ as1, const float* __restrict__ ad1,
    const float* __restrict__ as2, const float* __restrict__ ad2,
    ushort_t* __restrict__ Wt1, ushort_t* __restrict__ Wt2,
    ushort_t* __restrict__ attBt1, ushort_t* __restrict__ attBt2, int E)
{
    const int t = threadIdx.x;
    if (blockIdx.x < CNT_BLOCKS) {
        __shared__ int hist[256];
        hist[t] = 0;
        __syncthreads();
        const int chunk = (E + CNT_BLOCKS - 1) / CNT_BLOCKS;
        const int lo = blockIdx.x * chunk;
        const int hi = min(lo + chunk, E);
        for (int e = lo + t; e < hi; e += 256)
            atomicAdd(&hist[ei[E + e] >> 8], 1);
        __syncthreads();
        bhist[blockIdx.x * 256 + t] = hist[t];
        return;
    }
    const int idx = (blockIdx.x - CNT_BLOCKS) * 256 + t;
    const int n1 = FIN * HGAT_HC;
    const int n2 = HGAT_HC * HGAT_HC;
    if (idx < n1) {
        const int k = idx >> 8, c = idx & 255;
        Wt1[(size_t)c * FIN + k] = f2bf(W1[idx]);
    } else if (idx < n1 + n2) {
        const int j = idx - n1;
        const int k = j >> 8, c = j & 255;
        Wt2[(size_t)c * HGAT_HC + k] = f2bf(W2[j]);
    } else if (idx < n1 + n2 + FIN * 8) {
        att_fold_one(W1, as1, ad1, attBt1, FIN, idx - n1 - n2);
    } else if (idx < n1 + n2 + (FIN + HGAT_HC) * 8) {
        att_fold_one(W2, as2, ad2, attBt2, HGAT_HC, idx - n1 - n2 - FIN * 8);
    }
}

// ---------------------------------------------------------------------------
// Sum per-block hists + exclusive scan -> boff[0..256]; bcur init = boff.
// ---------------------------------------------------------------------------
__global__ __launch_bounds__(256) void bucket_scan_kernel(
    const int* __restrict__ bhist, int* __restrict__ boff,
    int* __restrict__ bcur)
{
    __shared__ int sm[256];
    const int t = threadIdx.x;
    int v = 0;
    for (int j = 0; j < CNT_BLOCKS; ++j) v += bhist[j * 256 + t];
    sm[t] = v;
    __syncthreads();
#pragma unroll
    for (int off = 1; off < 256; off <<= 1) {
        const int u = (t >= off) ? sm[t - off] : 0;
        __syncthreads();
        sm[t] += u;
        __syncthreads();
    }
    const int ex = sm[t] - v;
    boff[t] = ex;
    bcur[t] = ex;
    if (t == 255) boff[256] = sm[255];
}

// ---------------------------------------------------------------------------
// Scatter body: block takes a contiguous edge chunk, reserves per-bucket
// space wholesale, writes (src,dst) pairs into contiguous slices.
// ---------------------------------------------------------------------------
__device__ __forceinline__ void scatter_body(
    const int* __restrict__ ei, int* __restrict__ bcur,
    int2* __restrict__ staging, int E, int blk)
{
    __shared__ int hist[256];
    __shared__ int base[256];
    __shared__ int cur[256];
    const int t = threadIdx.x;
    hist[t] = 0;
    __syncthreads();

    const int chunk = 4096;
    const int lo = blk * chunk;
    const int hi = min(lo + chunk, E);

    for (int e = lo + t; e < hi; e += 256)
        atomicAdd(&hist[ei[E + e] >> 8], 1);
    __syncthreads();
    if (hist[t] > 0) base[t] = atomicAdd(&bcur[t], hist[t]);
    cur[t] = 0;
    __syncthreads();

    for (int e = lo + t; e < hi; e += 256) {
        const int s = ei[e];
        const int d = ei[E + e];
        const int b = d >> 8;
        const int r = atomicAdd(&cur[b], 1);
        staging[base[b] + r] = make_int2(s, d);
    }
}

// ---------------------------------------------------------------------------
// Bucket fill: one block per bucket.
// ---------------------------------------------------------------------------
__global__ __launch_bounds__(256) void bucket_fill_kernel(
    const int2* __restrict__ staging, const int* __restrict__ boff,
    int* __restrict__ rowptr, int* __restrict__ colsrc, int N, int E)
{
    __shared__ int deg[256];
    __shared__ int ssc[256];
    __shared__ int cur[256];
    const int t  = threadIdx.x;
    const int b  = blockIdx.x;
    const int lo = boff[b];
    const int hi = boff[b + 1];

    deg[t] = 0;
    __syncthreads();
    for (int e = lo + t; e < hi; e += 256)
        atomicAdd(&deg[staging[e].y & 255], 1);
    __syncthreads();

    const int v = deg[t];
    ssc[t] = v;
    __syncthreads();
#pragma unroll
    for (int off = 1; off < 256; off <<= 1) {
        const int u = (t >= off) ? ssc[t - off] : 0;
        __syncthreads();
        ssc[t] += u;
        __syncthreads();
    }
    const int pre  = ssc[t] - v;
    const int node = b * 256 + t;
    if (node < N) rowptr[node] = lo + pre;
    cur[t] = lo + pre;
    if (b == 0 && t == 0) rowptr[N] = E;
    __syncthreads();

    for (int e = lo + t; e < hi; e += 256) {
        const int2 sd = staging[e];
        const int pos = atomicAdd(&cur[sd.y & 255], 1);
        colsrc[pos] = sd.x;
    }
}

// ---------------------------------------------------------------------------
// GEMM body (device fn).  C[M,256] = A[M,K] @ Wt^T.  r12 structure.
// ---------------------------------------------------------------------------
template <int K, bool AF32>
__device__ __forceinline__ void gemm_body(
    const void* __restrict__ Av, const ushort_t* __restrict__ Bt,
    const ushort_t* __restrict__ attBt, ushort_t* __restrict__ Cb,
    float* __restrict__ a_src, float* __restrict__ a_dst, int M, int blk)
{
    constexpr int KK   = K / 32;
    constexpr int NPF  = K / 32;
    constexpr int BSTR = K + 8;
    constexpr int CSTR = 72;
    __shared__ ushort_t Bs[64 * BSTR];
    __shared__ ushort_t AttS[16 * BSTR];
    __shared__ ushort_t Cs[64 * CSTR];

    const int t  = threadIdx.x;
    const int w  = t >> 6;
    const int l  = t & 63;
    const int lg = l >> 4;
    const int lr = l & 15;
    const int rowbase = blk * 64 + w * 16;

    const int srow  = t & 63;
    const int cbase = (t >> 6) * (K / 4);

    short8 af[KK];
    {
        const int arow = rowbase + lr;
        const int gr   = arow < M ? arow : M - 1;
        if (AF32) {
            const float* Ap = (const float*)Av + (size_t)gr * K;
#pragma unroll
            for (int kk = 0; kk < KK; ++kk) {
                const float4 v0 = *reinterpret_cast<const float4*>(Ap + kk * 32 + lg * 8);
                const float4 v1 = *reinterpret_cast<const float4*>(Ap + kk * 32 + lg * 8 + 4);
                short8 s;
                s[0] = (short)f2bf(v0.x); s[1] = (short)f2bf(v0.y);
                s[2] = (short)f2bf(v0.z); s[3] = (short)f2bf(v0.w);
                s[4] = (short)f2bf(v1.x); s[5] = (short)f2bf(v1.y);
                s[6] = (short)f2bf(v1.z); s[7] = (short)f2bf(v1.w);
                af[kk] = s;
            }
        } else {
            const ushort_t* Ap = (const ushort_t*)Av + (size_t)gr * K;
#pragma unroll
            for (int kk = 0; kk < KK; ++kk)
                af[kk] = *reinterpret_cast<const short8*>(Ap + kk * 32 + lg * 8);
        }
    }

    {
        const int r  = t & 15;
        const int cb = (t >> 4) * (K / 16);
        const ushort_t* src = attBt + (size_t)r * K + cb;
        ushort_t*       dst = &AttS[r * BSTR + cb];
#pragma unroll
        for (int j = 0; j < K / 128; ++j)
            *reinterpret_cast<u16x8*>(dst + j * 8) =
                *reinterpret_cast<const u16x8*>(src + j * 8);
    }
    {
        const ushort_t* src = Bt + (size_t)srow * K + cbase;
        ushort_t*       dst = &Bs[srow * BSTR + cbase];
#pragma unroll
        for (int j = 0; j < NPF; ++j)
            *reinterpret_cast<u16x8*>(dst + j * 8) =
                *reinterpret_cast<const u16x8*>(src + j * 8);
    }
    __syncthreads();

    {
        f32x4 aacc = {0.f, 0.f, 0.f, 0.f};
#pragma unroll
        for (int kk = 0; kk < KK; ++kk) {
            const short8 bfr = *reinterpret_cast<const short8*>(
                &AttS[lr * BSTR + kk * 32 + lg * 8]);
            aacc = __builtin_amdgcn_mfma_f32_16x16x32_bf16(af[kk], bfr, aacc, 0, 0, 0);
        }
#pragma unroll
        for (int reg = 0; reg < 4; ++reg) {
            const int gm = rowbase + lg * 4 + reg;
            const float v = aacc[reg] + __shfl_xor(aacc[reg], 8);   // hi + lo
            if (lr < 8 && gm < M) {
                const int hh = lr >> 1;
                if (lr & 1) a_dst[gm * 4 + hh] = v * LOG2E;
                else        a_src[gm * 4 + hh] = v * LOG2E;
            }
        }
    }

    u16x8 pf[NPF];
#pragma unroll
    for (int head = 0; head < HGAT_H; ++head) {
        if (head < HGAT_H - 1) {
            const ushort_t* src =
                Bt + ((size_t)(head + 1) * 64 + srow) * K + cbase;
#pragma unroll
            for (int j = 0; j < NPF; ++j)
                pf[j] = *reinterpret_cast<const u16x8*>(src + j * 8);
        }

        f32x4 acc[4];
#pragma unroll
        for (int ct = 0; ct < 4; ++ct) acc[ct] = {0.f, 0.f, 0.f, 0.f};

#pragma unroll
        for (int kk = 0; kk < KK; ++kk) {
            short8 bfr[4];
#pragma unroll
            for (int ct = 0; ct < 4; ++ct)
                bfr[ct] = *reinterpret_cast<const short8*>(
                    &Bs[(ct * 16 + lr) * BSTR + kk * 32 + lg * 8]);
#pragma unroll
            for (int ct = 0; ct < 4; ++ct)
                acc[ct] = __builtin_amdgcn_mfma_f32_16x16x32_bf16(
                    af[kk], bfr[ct], acc[ct], 0, 0, 0);
        }

#pragma unroll
        for (int reg = 0; reg < 4; ++reg) {
            const int r = w * 16 + lg * 4 + reg;
#pragma unroll
            for (int ct = 0; ct < 4; ++ct)
                Cs[r * CSTR + ct * 16 + lr] = f2bf(acc[ct][reg]);
        }
        __syncthreads();

        const int n0 = head * 64;
        {
            const int cc = (t & 7) * 8;
#pragma unroll
            for (int it = 0; it < 2; ++it) {
                const int r  = (t >> 3) + it * 32;
                const int gm = blk * 64 + r;
                if (gm < M) {
                    const u16x8 val = *reinterpret_cast<const u16x8*>(&Cs[r * CSTR + cc]);
                    *reinterpret_cast<u16x8*>(&Cb[(size_t)gm * HGAT_HC + n0 + cc]) = val;
                }
            }
        }

        if (head < HGAT_H - 1) {
            ushort_t* dst = &Bs[srow * BSTR + cbase];
#pragma unroll
            for (int j = 0; j < NPF; ++j)
                *reinterpret_cast<u16x8*>(dst + j * 8) = pf[j];
        }
        __syncthreads();
    }
}

// ---------------------------------------------------------------------------
// Merged dispatch: blocks [0,SB) scatter edges; blocks [SB,..) run GEMM1.
// ---------------------------------------------------------------------------
__global__ __launch_bounds__(256) void scatter_gemm1_kernel(
    const int* __restrict__ ei, int* __restrict__ bcur,
    int2* __restrict__ staging, int E, int SB,
    const float* __restrict__ x, const ushort_t* __restrict__ Wt1,
    const ushort_t* __restrict__ attBt1, ushort_t* __restrict__ hb,
    float* __restrict__ a_src, float* __restrict__ a_dst, int M)
{
    if ((int)blockIdx.x < SB) {
        scatter_body(ei, bcur, staging, E, blockIdx.x);
        return;
    }
    gemm_body<FIN, true>(x, Wt1, attBt1, hb, a_src, a_dst, M,
                         blockIdx.x - SB);
}

__global__ __launch_bounds__(256) void gemm2_kernel(
    const ushort_t* __restrict__ A, const ushort_t* __restrict__ Wt2,
    const ushort_t* __restrict__ attBt2, ushort_t* __restrict__ hb,
    float* __restrict__ a_src, float* __restrict__ a_dst, int M)
{
    gemm_body<HGAT_HC, false>(A, Wt2, attBt2, hb, a_src, a_dst, M, blockIdx.x);
}

// ---------------------------------------------------------------------------
// CSR aggregate, TWO nodes per wave, uint4 gather (r14/r17 version).
// ---------------------------------------------------------------------------
template <int MODE>
__global__ __launch_bounds__(256) void aggregate_csr_kernel(
    const int* __restrict__ rowptr, const int* __restrict__ colsrc,
    const ushort_t* __restrict__ hb, const float* __restrict__ a_src,
    const float* __restrict__ a_dst, const float* __restrict__ bias,
    ushort_t* __restrict__ out, int N)
{
    const int wave = (blockIdx.x * 256 + threadIdx.x) >> 6;
    const int lane = threadIdx.x & 63;
    const int half = lane >> 5;
    const int hl   = lane & 31;
    const int d    = wave * 2 + half;
    if (d >= N) return;

    const int c0 = hl * 8;
    const int h  = hl >> 3;
    const float ad = a_dst[d * 4 + h];

    f32x2 a01 = {0.f, 0.f}, a23 = {0.f, 0.f}, a45 = {0.f, 0.f}, a67 = {0.f, 0.f};
    float den = 0.f;

    const int beg = rowptr[d], end = rowptr[d + 1];
    int i = beg;
    for (; i + 4 <= end; i += 4) {
        int   sv[4];
        float av[4];
        uint4 qv[4];
#pragma unroll
        for (int j = 0; j < 4; ++j) sv[j] = colsrc[i + j];
#pragma unroll
        for (int j = 0; j < 4; ++j) av[j] = a_src[sv[j] * 4 + h];
#pragma unroll
        for (int j = 0; j < 4; ++j)
            qv[j] = *reinterpret_cast<const uint4*>(&hb[(size_t)sv[j] * HGAT_HC + c0]);
#pragma unroll
        for (int j = 0; j < 4; ++j) {
            float ee = av[j] + ad;
            ee = fmaxf(ee, 0.2f * ee);
            const float wgt = __builtin_amdgcn_exp2f(ee);
            const f32x2 w2 = {wgt, wgt};
            a01 += w2 * f32x2{bflo(qv[j].x), bfhi(qv[j].x)};
            a23 += w2 * f32x2{bflo(qv[j].y), bfhi(qv[j].y)};
            a45 += w2 * f32x2{bflo(qv[j].z), bfhi(qv[j].z)};
            a67 += w2 * f32x2{bflo(qv[j].w), bfhi(qv[j].w)};
            den += wgt;
        }
    }
    for (; i < end; ++i) {
        const int s = colsrc[i];
        float ee = a_src[s * 4 + h] + ad;
        ee = fmaxf(ee, 0.2f * ee);
        const float wgt = __builtin_amdgcn_exp2f(ee);
        const uint4 q = *reinterpret_cast<const uint4*>(&hb[(size_t)s * HGAT_HC + c0]);
        const f32x2 w2 = {wgt, wgt};
        a01 += w2 * f32x2{bflo(q.x), bfhi(q.x)};
        a23 += w2 * f32x2{bflo(q.y), bfhi(q.y)};
        a45 += w2 * f32x2{bflo(q.z), bfhi(q.z)};
        a67 += w2 * f32x2{bflo(q.w), bfhi(q.w)};
        den += wgt;
    }
    {   // self loop
        float ee = a_src[d * 4 + h] + ad;
        ee = fmaxf(ee, 0.2f * ee);
        const float wgt = __builtin_amdgcn_exp2f(ee);
        const uint4 q = *reinterpret_cast<const uint4*>(&hb[(size_t)d * HGAT_HC + c0]);
        const f32x2 w2 = {wgt, wgt};
        a01 += w2 * f32x2{bflo(q.x), bfhi(q.x)};
        a23 += w2 * f32x2{bflo(q.y), bfhi(q.y)};
        a45 += w2 * f32x2{bflo(q.z), bfhi(q.z)};
        a67 += w2 * f32x2{bflo(q.w), bfhi(q.w)};
        den += wgt;
    }

    const float inv = 1.0f / den;
    float v[8] = {a01.x * inv, a01.y * inv, a23.x * inv, a23.y * inv,
                  a45.x * inv, a45.y * inv, a67.x * inv, a67.y * inv};

    if (MODE == 0) {
        const float4 b0 = *reinterpret_cast<const float4*>(&bias[c0]);
        const float4 b1 = *reinterpret_cast<const float4*>(&bias[c0 + 4]);
        v[0] += b0.x; v[1] += b0.y; v[2] += b0.z; v[3] += b0.w;
        v[4] += b1.x; v[5] += b1.y; v[6] += b1.z; v[7] += b1.w;
        u16x8 u;
#pragma unroll
        for (int j = 0; j < 8; ++j) {
            const float r = v[j] > 0.f ? v[j] : expm1f(v[j]);
            u[j] = f2bf(r);
        }
        *reinterpret_cast<u16x8*>(&out[(size_t)d * HGAT_HC + c0]) = u;
    } else {
#pragma unroll
        for (int j = 0; j < 8; ++j) {
            v[j] += __shfl_xor(v[j], 8);
            v[j] += __shfl_xor(v[j], 16);
        }
        if (hl < 8) {
            const int c = hl * 8;
            const float4 b0 = *reinterpret_cast<const float4*>(&bias[c]);
            const float4 b1 = *reinterpret_cast<const float4*>(&bias[c + 4]);
            const float bb[8] = {b0.x, b0.y, b0.z, b0.w, b1.x, b1.y, b1.z, b1.w};
            u16x8 u;
#pragma unroll
            for (int j = 0; j < 8; ++j) {
                float r = 0.25f * v[j] + bb[j];
                r = r > 0.f ? r : expm1f(r);
                u[j] = f2bf(r);
            }
            *reinterpret_cast<u16x8*>(&out[(size_t)d * HGAT_C + c]) = u;
        }
    }
}

// ---------------------------------------------------------------------------
// Pool stage A + fused stage B.
// ---------------------------------------------------------------------------
__device__ __forceinline__ int lower_bound_batch(
    const int* __restrict__ batch, int N, int key)
{
    int lo = 0, hi = N;
    while (lo < hi) {
        const int mid = (lo + hi) >> 1;
        if (batch[mid] < key) lo = mid + 1; else hi = mid;
    }
    return lo;
}

__global__ __launch_bounds__(256) void pool_partial_kernel(
    const ushort_t* __restrict__ hfin, const int* __restrict__ batch,
    float* __restrict__ partial, int N)
{
    const int g   = blockIdx.x >> 3;
    const int s   = blockIdx.x & 7;
    const int t   = threadIdx.x;
    const int c   = t & 63;
    const int sub = t >> 6;

    const int beg = lower_bound_batch(batch, N, g);
    const int end = lower_bound_batch(batch, N, g + 1);
    const int len = end - beg;
    const int sl  = (len + 7) >> 3;
    const int sb  = beg + s * sl;
    const int se  = sb + sl < end ? sb + sl : end;

    float acc = 0.f;
    for (int n = sb + sub; n < se; n += 4)
        acc += bf2f(hfin[(size_t)n * HGAT_C + c]);

    __shared__ float sm[256];
    sm[t] = acc;
    __syncthreads();
    if (sub == 0)
        partial[(size_t)(g * 8 + s) * HGAT_C + c] =
            sm[c] + sm[64 + c] + sm[128 + c] + sm[192 + c];
}

__global__ __launch_bounds__(64) void pool_final_fused_kernel(
    const float* __restrict__ partial, const int* __restrict__ batch,
    const float* __restrict__ Wa, const float* __restrict__ ba,
    float* __restrict__ out, int N)
{
    const int g = blockIdx.x;
    const int c = threadIdx.x;
    const int beg = lower_bound_batch(batch, N, g);
    const int end = lower_bound_batch(batch, N, g + 1);
    float s = 0.f;
#pragma unroll
    for (int k = 0; k < 8; ++k)
        s += partial[(size_t)(g * 8 + k) * HGAT_C + c];
    s /= fmaxf((float)(end - beg), 1.0f);

    __shared__ float pr[HGAT_C];
    pr[c] = s;
    __syncthreads();
    if (c < NACT) {
        float o = ba[c];
#pragma unroll
        for (int cc = 0; cc < HGAT_C; ++cc)
            o += pr[cc] * Wa[cc * NACT + c];
        out[g * NACT + c] = o;
    }
}

// ---------------------------------------------------------------------------
extern "C" void kernel_launch(void* const* d_in, const int* in_sizes, int n_in,
                              void* d_out, int out_size, void* d_ws, size_t ws_size,
                              hipStream_t stream)
{
    const float* x     = (const float*)d_in[0];
    const int*   ei    = (const int*)d_in[1];
    const int*   batch = (const int*)d_in[2];
    const float* W1    = (const float*)d_in[5];
    const float* as1   = (const float*)d_in[6];
    const float* ad1   = (const float*)d_in[7];
    const float* b1    = (const float*)d_in[8];
    const float* W2    = (const float*)d_in[9];
    const float* as2   = (const float*)d_in[10];
    const float* ad2   = (const float*)d_in[11];
    const float* b2    = (const float*)d_in[12];
    const float* Wa    = (const float*)d_in[13];
    const float* ba    = (const float*)d_in[14];

    const int N = in_sizes[0] / FIN;
    const int E = in_sizes[1] / 2;

    char* ws = (char*)d_ws;
    size_t off = 0;
    auto alloc = [&](size_t bytes) -> void* {
        void* p = ws + off;
        off += (bytes + 255) & ~(size_t)255;
        return p;
    };
    ushort_t* hb      = (ushort_t*)alloc((size_t)N * HGAT_HC * 2);
    ushort_t* hpost   = (ushort_t*)alloc((size_t)N * HGAT_HC * 2);
    ushort_t* Wt1     = (ushort_t*)alloc((size_t)FIN * HGAT_HC * 2);
    ushort_t* Wt2     = (ushort_t*)alloc((size_t)HGAT_HC * HGAT_HC * 2);
    ushort_t* attBt1  = (ushort_t*)alloc((size_t)16 * FIN * 2);
    ushort_t* attBt2  = (ushort_t*)alloc((size_t)16 * HGAT_HC * 2);
    float*    a_src   = (float*)alloc((size_t)N * 4 * 4);
    float*    a_dst   = (float*)alloc((size_t)N * 4 * 4);
    int*      rowptr  = (int*)alloc((size_t)(N + 1) * 4);
    int*      colsrc  = (int*)alloc((size_t)E * 4);
    int2*     staging = (int2*)alloc((size_t)E * 8);
    int*      bhist   = (int*)alloc((size_t)CNT_BLOCKS * 256 * 4);
    int*      boff    = (int*)alloc(257 * 4);
    int*      bcur    = (int*)alloc(256 * 4);
    float*    partial = (float*)alloc((size_t)NGRAPHS * 8 * HGAT_C * 4);
    ushort_t* hfin    = hpost;
    (void)ws_size; (void)n_in; (void)out_size;

    const int gemmBlocks = (N + 63) / 64;
    const int aggBlocks  = (N + 7) / 8;
    const int NBKT       = (N + 255) >> 8;
    const int SB         = (E + 4095) / 4096;
    const int prepTot    = FIN * HGAT_HC + HGAT_HC * HGAT_HC + (FIN + HGAT_HC) * 8;
    const int prepBlocks = (prepTot + 255) / 256;

    // ---------------- dispatch 1: edge histograms + prep ----------------
    bucket_count_prep_kernel<<<CNT_BLOCKS + prepBlocks, 256, 0, stream>>>(
        ei, bhist, W1, W2, as1, ad1, as2, ad2, Wt1, Wt2, attBt1, attBt2, E);

    // ---------------- dispatch 2: hist-sum + bucket scan ----------------
    bucket_scan_kernel<<<1, 256, 0, stream>>>(bhist, boff, bcur);

    // ---------------- dispatch 3: scatter || GEMM1 ----------------
    scatter_gemm1_kernel<<<SB + gemmBlocks, 256, 0, stream>>>(
        ei, bcur, staging, E, SB, x, Wt1, attBt1, hb, a_src, a_dst, N);

    // ---------------- dispatch 4: bucket fill ----------------
    bucket_fill_kernel<<<NBKT, 256, 0, stream>>>(
        staging, boff, rowptr, colsrc, N, E);

    // ---------------- layer 1 aggregate ----------------
    aggregate_csr_kernel<0><<<aggBlocks, 256, 0, stream>>>(
        rowptr, colsrc, hb, a_src, a_dst, b1, hpost, N);

    // ---------------- layer 2 ----------------
    gemm2_kernel<<<gemmBlocks, 256, 0, stream>>>(
        hpost, Wt2, attBt2, hb, a_src, a_dst, N);
    aggregate_csr_kernel<1><<<aggBlocks, 256, 0, stream>>>(
        rowptr, colsrc, hb, a_src, a_dst, b2, hfin, N);

    // ---------------- pool + final ----------------
    pool_partial_kernel<<<NGRAPHS * 8, 256, 0, stream>>>(hfin, batch, partial, N);
    pool_final_fused_kernel<<<NGRAPHS, 64, 0, stream>>>(
        partial, batch, Wa, ba, (float*)d_out, N);
}